// Round 22
// baseline (177.125 us; speedup 1.0000x reference)
//
#include <hip/hip_runtime.h>
#include <hip/hip_bf16.h>

#define NU 262144
#define GG 128
#define PG 134          // padded field side (128 + 2*3)
#define DD 128
#define NCELL 4096      // 16^3 cells of 8^3 voxels

typedef __attribute__((ext_vector_type(8))) short short8;   // 8 bf16 MFMA frag
typedef __attribute__((ext_vector_type(4))) float f32x4;

union Frag { short8 s; unsigned u[4]; };

// fp32 -> bf16 RNE (prep kernels)
__device__ __forceinline__ unsigned short f2b(float f) {
  union { float f; unsigned u; } v; v.f = f;
  unsigned r = v.u + 0x7fffu + ((v.u >> 16) & 1u);
  return (unsigned short)(r >> 16);
}
// packed fp32x2 -> bf16x2 (RNE HW instr)
__device__ __forceinline__ unsigned cvtpk(float lo, float hi) {
  unsigned r;
  asm("v_cvt_pk_bf16_f32 %0, %1, %2" : "=v"(r) : "v"(lo), "v"(hi));
  return r;
}
__device__ __forceinline__ float unplo(unsigned w) {
  union { unsigned u; float f; } v; v.u = w << 16; return v.f;
}
__device__ __forceinline__ float unphi(unsigned w) {
  union { unsigned u; float f; } v; v.u = w & 0xffff0000u; return v.f;
}

__device__ __forceinline__ float fast_tanh(float x) {
  float e = __expf(fabsf(x) * 2.0f);
  float r = __frcp_rn(e + 1.0f);
  return copysignf(fmaf(-2.0f, r, 1.0f), x);
}

// 128 neighborhood offsets = 18 z-rows of 7 + one 2-elem stub (+1 dead row)
struct alignas(16) RowdT { int v[20]; };
static constexpr RowdT mkrowd() {
  RowdT t{};
  for (int r = 0; r < 20; ++r) {
    int rr = (r < 18) ? r : 18;
    int di = (rr < 18) ? (-3 + rr / 7) : -1;
    int dj = (rr < 18) ? (-3 + rr % 7) : 1;
    t.v[r] = (di * PG + dj) * PG - 3;
  }
  return t;
}
__device__ constexpr RowdT ROWD = mkrowd();

__device__ __forceinline__ int cell_of(float px, float py, float pz) {
  int cx = min(max((int)px, 0), GG - 1) >> 3;
  int cy = min(max((int)py, 0), GG - 1) >> 3;
  int cz = min(max((int)pz, 0), GG - 1) >> 3;
  return (cx << 8) | (cy << 4) | cz;
}

// ---------------- prep 1: clamped pad + bf16 field ----------------
__global__ void prep_field(const float* __restrict__ f, unsigned short* __restrict__ fp) {
  int idx = blockIdx.x * 256 + threadIdx.x;
  if (idx >= PG * PG * PG) return;
  int z = idx % PG, t = idx / PG;
  int y = t % PG, x = t / PG;
  int xx = min(max(x - 3, 0), GG - 1);
  int yy = min(max(y - 3, 0), GG - 1);
  int zz = min(max(z - 3, 0), GG - 1);
  fp[idx] = f2b(f[(xx * GG + yy) * GG + zz]);
}

// ---------------- prep 2: weight wall (13 x 8KB) + cursor zero ----------------
__global__ void prep_w(const float* __restrict__ W1, const float* __restrict__ W2,
                       unsigned short* __restrict__ wall, int* __restrict__ cursor) {
  int idx = blockIdx.x * 256 + threadIdx.x;
  if (cursor && idx < NCELL) cursor[idx] = 0;
  if (idx >= 6656) return;
  int kt = idx >> 9, nt = (idx >> 6) & 7, ln = idx & 63;
  int n = nt * 16 + (ln & 15), lg = ln >> 4;
  short8 s;
  if (kt < 4) {
    int k0 = kt * 32 + lg * 8;
#pragma unroll
    for (int j = 0; j < 8; ++j) s[j] = (short)f2b(W1[(k0 + j) * DD + n]);
  } else if (kt < 9) {
    int r = (kt - 4) * 4 + lg;                 // 0..19
#pragma unroll
    for (int j = 0; j < 8; ++j) {
      bool valid = (r < 18 && j < 7) || (r == 18 && j < 2);
      int row = 128 + ((r < 18) ? (r * 7 + j) : (126 + j));
      s[j] = valid ? (short)f2b(W1[row * DD + n]) : (short)0;
    }
  } else {
    int k0 = (kt - 9) * 32 + lg * 8;
#pragma unroll
    for (int j = 0; j < 8; ++j) s[j] = (short)f2b(W2[(k0 + j) * DD + n]);
  }
  ((short8*)wall)[idx] = s;
}

// ---------------- counting sort by cell (pos/offs only; sig untouched) ----------------
__global__ void hist_k(const float* __restrict__ pos, int* __restrict__ cursor) {
  int u = blockIdx.x * 256 + threadIdx.x;
  atomicAdd(&cursor[cell_of(pos[u * 3], pos[u * 3 + 1], pos[u * 3 + 2])], 1);
}
__global__ void scan_k(int* __restrict__ cursor) {
  __shared__ int sums[256];
  int t = threadIdx.x;
  int local[16];
  int partial = 0;
#pragma unroll
  for (int j = 0; j < 16; ++j) { local[j] = cursor[t * 16 + j]; partial += local[j]; }
  sums[t] = partial;
  __syncthreads();
  for (int off = 1; off < 256; off <<= 1) {
    int v = (t >= off) ? sums[t - off] : 0;
    __syncthreads();
    sums[t] += v;
    __syncthreads();
  }
  int excl = sums[t] - partial;
#pragma unroll
  for (int j = 0; j < 16; ++j) { cursor[t * 16 + j] = excl; excl += local[j]; }
}
__global__ void scatter_k(const float* __restrict__ pos, const float* __restrict__ offs,
                          int* __restrict__ cursor, int* __restrict__ perm,
                          float* __restrict__ posP, float* __restrict__ offsP) {
  int u = blockIdx.x * 256 + threadIdx.x;
  float px = pos[u * 3 + 0], py = pos[u * 3 + 1], pz = pos[u * 3 + 2];
  int dst = atomicAdd(&cursor[cell_of(px, py, pz)], 1);
  perm[dst] = u;
  posP[dst * 3 + 0] = px; posP[dst * 3 + 1] = py; posP[dst * 3 + 2] = pz;
  offsP[dst * 3 + 0] = offs[u * 3 + 0];
  offsP[dst * 3 + 1] = offs[u * 3 + 1];
  offsP[dst * 3 + 2] = offs[u * 3 + 2];
}

// ---------------- main: 8 waves/block, wave = 16 units x {ev0, ev1} ----------------
// r21 structure. SORT mode: pos/offs pre-permuted (coalesced), sig gathered via
// perm (same HBM line count), outputs scattered via perm; field gathers cell-local.
template<bool SORT>
__global__ __launch_bounds__(512, 4) void atu_main(
    const float* __restrict__ pos, const float* __restrict__ sig,
    const float* __restrict__ offs, const int* __restrict__ perm,
    const float* __restrict__ b1, const float* __restrict__ b2,
    const unsigned short* __restrict__ fpad, const unsigned short* __restrict__ wall,
    float* __restrict__ out_stab, float* __restrict__ out_pos)
{
  __shared__ unsigned short ldsw[2][8192];           // 2 x 16KB weight buffers
  __shared__ unsigned short lds12[4096];             // 8KB dedicated kt12 slot
  __shared__ alignas(16) unsigned short ns[8][2048]; // 8 x 4KB per-wave sig stash
  const int tid  = threadIdx.x;
  const int lane = tid & 63;
  const int lg   = lane >> 4, lm = lane & 15;
  const int wid  = tid >> 6;
  int bid = blockIdx.x;
  int swz = (bid & 7) * 256 + (bid >> 3);      // XCD-bijective (2048 % 8 == 0)
  const int ub = swz * 128 + wid * 16;         // 16 units per wave
  const int un = ub + lm;                      // block-local unit slot
  const int pv = SORT ? perm[un] : un;         // original unit index (sig + outputs)
  char* nsb = (char*)&ns[wid][0];
  const char* wallb = (const char*)wall;
  const char* fpadb = (const char*)fpad;

  // gather bases: ev0 / ev1 (pos/offs coalesced; permuted in SORT mode)
  int abase[2];
  {
    float px = pos[un * 3 + 0], py = pos[un * 3 + 1], pz = pos[un * 3 + 2];
    float qx = px + offs[un * 3 + 0], qy = py + offs[un * 3 + 1], qz = pz + offs[un * 3 + 2];
    int ax = min(max((int)px, 0), GG - 1), ay = min(max((int)py, 0), GG - 1), az = min(max((int)pz, 0), GG - 1);
    int bx = min(max((int)qx, 0), GG - 1), by = min(max((int)qy, 0), GG - 1), bz = min(max((int)qz, 0), GG - 1);
    abase[0] = ((ax + 3) * PG + (ay + 3)) * PG + (az + 3);
    abase[1] = ((bx + 3) * PG + (by + 3)) * PG + (bz + 3);
  }

  // async weight staging: pair (KTA, KTA+1) -> buffer H.
#define GLL2(KTA, H)                                                              \
  __builtin_amdgcn_global_load_lds(                                               \
      (const unsigned*)(wallb + (((KTA) * 512 + tid) * 16)),                      \
      (unsigned*)((char*)&ldsw[H][0] + wid * 1024), 16, 0, 0);                    \
  __builtin_amdgcn_global_load_lds(                                               \
      (const unsigned*)(wallb + ((((KTA) + 1) * 512 + tid) * 16)),                \
      (unsigned*)((char*)&ldsw[H][0] + 8192 + wid * 1024), 16, 0, 0);

  // ---- prologue: stage pair (0,1) AND kt12; preload sig kt0 and ALL 10 rows ----
  GLL2(0, 0)
  __builtin_amdgcn_global_load_lds(
      (const unsigned*)(wallb + ((12 * 512 + tid) * 16)),
      (unsigned*)((char*)lds12 + wid * 1024), 16, 0, 0);
  f32x4 spa = *(const f32x4*)(sig + (size_t)pv * DD + lg * 8);
  f32x4 spb = *(const f32x4*)(sig + (size_t)pv * DD + lg * 8 + 4);
  short8 rw[5][2];                              // all rows, both evs, in flight now
#pragma unroll
  for (int k = 0; k < 5; ++k) {
    int rd = ROWD.v[k * 4 + lg];
    rw[k][0] = *(const short8*)(fpadb + 2 * (size_t)(abase[0] + rd));
    rw[k][1] = *(const short8*)(fpadb + 2 * (size_t)(abase[1] + rd));
  }

  // acc C-init = b1 (bias folded)
  f32x4 acc[8][2];
#pragma unroll
  for (int nt = 0; nt < 8; ++nt) acc[nt][0] = *(const f32x4*)(b1 + nt * 16 + lg * 4);
  f32x4 acc2[8][2];
  unsigned Q[2][8][2];

  __syncthreads();   // barrier #1: pair (0,1) + kt12 landed

#define SIG_KT(KT, HALF)                                                          \
  {                                                                               \
    f32x4 na, nb;                                                                 \
    if ((KT) < 3) {                                                               \
      na = *(const f32x4*)(sig + (size_t)pv * DD + ((KT) + 1) * 32 + lg * 8);     \
      nb = *(const f32x4*)(sig + (size_t)pv * DD + ((KT) + 1) * 32 + lg * 8 + 4); \
    }                                                                             \
    Frag B;                                                                       \
    B.u[0] = cvtpk(spa[0], spa[1]); B.u[1] = cvtpk(spa[2], spa[3]);               \
    B.u[2] = cvtpk(spb[0], spb[1]); B.u[3] = cvtpk(spb[2], spb[3]);               \
    *(short8*)(nsb + ((KT) * 4 + lg) * 256 + lm * 16) = B.s;                      \
    const char* buf = (const char*)&ldsw[HALF][0] + (((KT) & 1) ? 8192 : 0);      \
    _Pragma("unroll")                                                             \
    for (int nt = 0; nt < 8; ++nt) {                                              \
      short8 af = *(const short8*)(buf + (nt * 64 + lane) * 16);                  \
      acc[nt][0] = __builtin_amdgcn_mfma_f32_16x16x32_bf16(af, B.s, acc[nt][0], 0, 0, 0); \
    }                                                                             \
    if ((KT) < 3) { spa = na; spb = nb; }                                         \
  }

#define ROW_KT(KT, HALF)                                                          \
  {                                                                               \
    const char* buf = (const char*)&ldsw[HALF][0] + (((KT) & 1) ? 8192 : 0);      \
    _Pragma("unroll")                                                             \
    for (int nt = 0; nt < 8; ++nt) {                                              \
      short8 af = *(const short8*)(buf + (nt * 64 + lane) * 16);                  \
      acc[nt][0] = __builtin_amdgcn_mfma_f32_16x16x32_bf16(af, rw[(KT) - 4][0], acc[nt][0], 0, 0, 0); \
      acc[nt][1] = __builtin_amdgcn_mfma_f32_16x16x32_bf16(af, rw[(KT) - 4][1], acc[nt][1], 0, 0, 0); \
    }                                                                             \
  }

#define G2_KT(KT, BUF)                                                            \
  {                                                                               \
    constexpr int kb = (KT) - 9;                                                  \
    Frag W[2];                                                                    \
    _Pragma("unroll")                                                             \
    for (int ut = 0; ut < 2; ++ut) {                                              \
      int qa0 = (int)Q[ut][2 * kb][0],     qa1 = (int)Q[ut][2 * kb][1];           \
      int qb0 = (int)Q[ut][2 * kb + 1][0], qb1 = (int)Q[ut][2 * kb + 1][1];       \
      int r00 = __builtin_amdgcn_ds_bpermute(ad0, qa0);                           \
      int r01 = __builtin_amdgcn_ds_bpermute(ad0, qa1);                           \
      int r10 = __builtin_amdgcn_ds_bpermute(ad1, qa0);                           \
      int r11 = __builtin_amdgcn_ds_bpermute(ad1, qa1);                           \
      int s00 = __builtin_amdgcn_ds_bpermute(ad0, qb0);                           \
      int s01 = __builtin_amdgcn_ds_bpermute(ad0, qb1);                           \
      int s10 = __builtin_amdgcn_ds_bpermute(ad1, qb0);                           \
      int s11 = __builtin_amdgcn_ds_bpermute(ad1, qb1);                           \
      W[ut].u[0] = (unsigned)(hi ? s00 : r00);                                    \
      W[ut].u[1] = (unsigned)(hi ? s01 : r01);                                    \
      W[ut].u[2] = (unsigned)(hi ? s10 : r10);                                    \
      W[ut].u[3] = (unsigned)(hi ? s11 : r11);                                    \
    }                                                                             \
    const char* buf = (BUF);                                                      \
    _Pragma("unroll")                                                             \
    for (int nt = 0; nt < 8; ++nt) {                                              \
      short8 af = *(const short8*)(buf + (nt * 64 + lane) * 16);                  \
      acc2[nt][0] = __builtin_amdgcn_mfma_f32_16x16x32_bf16(af, W[0].s, acc2[nt][0], 0, 0, 0); \
      acc2[nt][1] = __builtin_amdgcn_mfma_f32_16x16x32_bf16(af, W[1].s, acc2[nt][1], 0, 0, 0); \
    }                                                                             \
  }

  const int ad0 = ((((2 * lg) & 3) * 16) + lm) * 4;       // bpermute byte addrs
  const int ad1 = ((((2 * lg + 1) & 3) * 16) + lm) * 4;
  const bool hi = (lg >= 2);

  // P0: kts 0,1 from buf0; prefetch pair (2,3) -> buf1
  GLL2(2, 1)
  SIG_KT(0, 0) SIG_KT(1, 0)
  __syncthreads();

  // P1: kts 2,3 from buf1; prefetch pair (4,5) -> buf0
  GLL2(4, 0)
  SIG_KT(2, 1) SIG_KT(3, 1)
  __syncthreads();

  // sig contribution is shared by both evs (b1 carried along)
#pragma unroll
  for (int nt = 0; nt < 8; ++nt) acc[nt][1] = acc[nt][0];

  // P2: kts 4,5 from buf0; prefetch pair (6,7) -> buf1
  GLL2(6, 1)
  ROW_KT(4, 0) ROW_KT(5, 0)
  __syncthreads();

  // P3: kts 6,7 from buf1; prefetch pair (8,9) -> buf0
  GLL2(8, 0)
  ROW_KT(6, 1) ROW_KT(7, 1)
  __syncthreads();

  // P4: kt8 (row) + tanh/pack + kt9 (G2) from buf0; prefetch pair (10,11) -> buf1
  GLL2(10, 1)
  ROW_KT(8, 0)

  // tanh + pack h (bias already in acc)
#pragma unroll
  for (int nt = 0; nt < 8; ++nt) {
#pragma unroll
    for (int ut = 0; ut < 2; ++ut) {
      float h0 = fast_tanh(acc[nt][ut][0]);
      float h1 = fast_tanh(acc[nt][ut][1]);
      float h2 = fast_tanh(acc[nt][ut][2]);
      float h3 = fast_tanh(acc[nt][ut][3]);
      Q[ut][nt][0] = cvtpk(h0, h1);
      Q[ut][nt][1] = cvtpk(h2, h3);
    }
  }
#pragma unroll
  for (int nt = 0; nt < 8; ++nt) {
    f32x4 b2v = *(const f32x4*)(b2 + nt * 16 + lg * 4);
    acc2[nt][0] = b2v; acc2[nt][1] = b2v;
  }

  G2_KT(9, (const char*)&ldsw[0][0] + 8192)
  __syncthreads();

  // P5: kts 10,11 from buf1; kt12 already resident in its own slot -> no more syncs
  G2_KT(10, (const char*)&ldsw[1][0])
  G2_KT(11, (const char*)&ldsw[1][0] + 8192)
  G2_KT(12, (const char*)lds12)

  // ---- || resp - sig ||^2 (sig bf16 from per-wave LDS stash) ----
  float ssq[2] = {0.f, 0.f};
#pragma unroll
  for (int nt = 0; nt < 8; ++nt) {
    unsigned long long w64 = *(const unsigned long long*)
        (nsb + (nt * 2 + (lg >> 1)) * 256 + lm * 16 + (lg & 1) * 8);
    unsigned w0 = (unsigned)w64, w1 = (unsigned)(w64 >> 32);
    float sv0 = unplo(w0), sv1 = unphi(w0);
    float sv2 = unplo(w1), sv3 = unphi(w1);
#pragma unroll
    for (int ut = 0; ut < 2; ++ut) {
      float d0 = acc2[nt][ut][0] - sv0;
      float d1 = acc2[nt][ut][1] - sv1;
      float d2 = acc2[nt][ut][2] - sv2;
      float d3 = acc2[nt][ut][3] - sv3;
      ssq[ut] = fmaf(d0, d0, ssq[ut]);
      ssq[ut] = fmaf(d1, d1, ssq[ut]);
      ssq[ut] = fmaf(d2, d2, ssq[ut]);
      ssq[ut] = fmaf(d3, d3, ssq[ut]);
    }
  }
  ssq[0] += __shfl_xor(ssq[0], 16, 64); ssq[0] += __shfl_xor(ssq[0], 32, 64);
  ssq[1] += __shfl_xor(ssq[1], 16, 64); ssq[1] += __shfl_xor(ssq[1], 32, 64);

  // ---- accept / outputs: lanes 0..15; scatter via pv in SORT mode ----
  if (lane < 16) {
    float px = pos[un * 3 + 0], py = pos[un * 3 + 1], pz = pos[un * 3 + 2];
    float ox = offs[un * 3 + 0], oy = offs[un * 3 + 1], oz = offs[un * 3 + 2];
    bool ok = ssq[1] <= ssq[0];
    out_stab[pv] = sqrtf(ok ? ssq[1] : ssq[0]);
    out_pos[pv * 3 + 0] = ok ? px + ox : px;
    out_pos[pv * 3 + 1] = ok ? py + oy : py;
    out_pos[pv * 3 + 2] = ok ? pz + oz : pz;
  }
#undef GLL2
#undef SIG_KT
#undef ROW_KT
#undef G2_KT
}

extern "C" void kernel_launch(void* const* d_in, const int* in_sizes, int n_in,
                              void* d_out, int out_size, void* d_ws, size_t ws_size,
                              hipStream_t stream) {
  const float* field = (const float*)d_in[0];
  const float* pos   = (const float*)d_in[1];
  const float* sig   = (const float*)d_in[2];
  const float* offs  = (const float*)d_in[3];
  const float* W1    = (const float*)d_in[4];
  const float* b1    = (const float*)d_in[5];
  const float* W2    = (const float*)d_in[6];
  const float* b2    = (const float*)d_in[7];
  float* out_stab = (float*)d_out;
  float* out_pos  = out_stab + NU;

  char* ws = (char*)d_ws;
  unsigned short* fpad  = (unsigned short*)ws;                 // 4,812,208 B (+slack)
  unsigned short* wall  = (unsigned short*)(ws + 4812800);     // 106,496 B (13 x 8KB)
  float*          posP  = (float*)(ws + 4919296);              // 3,145,728 B
  float*          offsP = (float*)(ws + 8065024);              // 3,145,728 B
  int*            perm  = (int*)(ws + 11210752);               // 1,048,576 B
  int*            cursor= (int*)(ws + 12259328);               // 16,384 B
  const size_t need_sort = 12275712ull;

  prep_field<<<(PG * PG * PG + 255) / 256, 256, 0, stream>>>(field, fpad);

  if (ws_size >= need_sort) {
    prep_w<<<26, 256, 0, stream>>>(W1, W2, wall, cursor);
    hist_k<<<NU / 256, 256, 0, stream>>>(pos, cursor);
    scan_k<<<1, 256, 0, stream>>>(cursor);
    scatter_k<<<NU / 256, 256, 0, stream>>>(pos, offs, cursor, perm, posP, offsP);
    atu_main<true><<<NU / 128, 512, 0, stream>>>(posP, sig, offsP, perm, b1, b2,
                                                 fpad, wall, out_stab, out_pos);
  } else {
    prep_w<<<26, 256, 0, stream>>>(W1, W2, wall, nullptr);
    atu_main<false><<<NU / 128, 512, 0, stream>>>(pos, sig, offs, nullptr, b1, b2,
                                                  fpad, wall, out_stab, out_pos);
  }
}

// Round 23
// 134.169 us; speedup vs baseline: 1.3202x; 1.3202x over previous
//
#include <hip/hip_runtime.h>
#include <hip/hip_bf16.h>

#define NU 262144
#define GG 128
#define PG 134          // padded field side (128 + 2*3)
#define DD 128

typedef __attribute__((ext_vector_type(8))) short short8;   // 8 bf16 MFMA frag
typedef __attribute__((ext_vector_type(4))) float f32x4;

union Frag { short8 s; unsigned u[4]; };

// fp32 -> bf16 RNE (prep kernels)
__device__ __forceinline__ unsigned short f2b(float f) {
  union { float f; unsigned u; } v; v.f = f;
  unsigned r = v.u + 0x7fffu + ((v.u >> 16) & 1u);
  return (unsigned short)(r >> 16);
}
// packed fp32x2 -> bf16x2 (RNE HW instr)
__device__ __forceinline__ unsigned cvtpk(float lo, float hi) {
  unsigned r;
  asm("v_cvt_pk_bf16_f32 %0, %1, %2" : "=v"(r) : "v"(lo), "v"(hi));
  return r;
}
__device__ __forceinline__ float unplo(unsigned w) {
  union { unsigned u; float f; } v; v.u = w << 16; return v.f;
}
__device__ __forceinline__ float unphi(unsigned w) {
  union { unsigned u; float f; } v; v.u = w & 0xffff0000u; return v.f;
}

__device__ __forceinline__ float fast_tanh(float x) {
  float e = __expf(fabsf(x) * 2.0f);
  float r = __frcp_rn(e + 1.0f);
  return copysignf(fmaf(-2.0f, r, 1.0f), x);
}

// 128 neighborhood offsets = 18 z-rows of 7 + one 2-elem stub (+1 dead row)
struct alignas(16) RowdT { int v[20]; };
static constexpr RowdT mkrowd() {
  RowdT t{};
  for (int r = 0; r < 20; ++r) {
    int rr = (r < 18) ? r : 18;
    int di = (rr < 18) ? (-3 + rr / 7) : -1;
    int dj = (rr < 18) ? (-3 + rr % 7) : 1;
    t.v[r] = (di * PG + dj) * PG - 3;
  }
  return t;
}
__device__ constexpr RowdT ROWD = mkrowd();

// ---------------- prep 1: clamped pad + bf16 field ----------------
__global__ void prep_field(const float* __restrict__ f, unsigned short* __restrict__ fp) {
  int idx = blockIdx.x * 256 + threadIdx.x;
  if (idx >= PG * PG * PG) return;
  int z = idx % PG, t = idx / PG;
  int y = t % PG, x = t / PG;
  int xx = min(max(x - 3, 0), GG - 1);
  int yy = min(max(y - 3, 0), GG - 1);
  int zz = min(max(z - 3, 0), GG - 1);
  fp[idx] = f2b(f[(xx * GG + yy) * GG + zz]);
}

// ---------------- prep 2: weight wall (13 x 8KB) ----------------
// kt 0-3: W1 sig half; kt 4-8: W1 gather rows (reordered, zero-padded); kt 9-12: W2.
__global__ void prep_w(const float* __restrict__ W1, const float* __restrict__ W2,
                       unsigned short* __restrict__ wall) {
  int idx = blockIdx.x * 256 + threadIdx.x;
  if (idx >= 6656) return;
  int kt = idx >> 9, nt = (idx >> 6) & 7, ln = idx & 63;
  int n = nt * 16 + (ln & 15), lg = ln >> 4;
  short8 s;
  if (kt < 4) {
    int k0 = kt * 32 + lg * 8;
#pragma unroll
    for (int j = 0; j < 8; ++j) s[j] = (short)f2b(W1[(k0 + j) * DD + n]);
  } else if (kt < 9) {
    int r = (kt - 4) * 4 + lg;                 // 0..19
#pragma unroll
    for (int j = 0; j < 8; ++j) {
      bool valid = (r < 18 && j < 7) || (r == 18 && j < 2);
      int row = 128 + ((r < 18) ? (r * 7 + j) : (126 + j));
      s[j] = valid ? (short)f2b(W1[row * DD + n]) : (short)0;
    }
  } else {
    int k0 = (kt - 9) * 32 + lg * 8;
#pragma unroll
    for (int j = 0; j < 8; ++j) s[j] = (short)f2b(W2[(k0 + j) * DD + n]);
  }
  ((short8*)wall)[idx] = s;
}

// ---------------- main: 8 waves/block, wave = 16 units x {ev0, ev1} ----------------
// Best-known configuration (r21): async weight staging (global_load_lds, 2x16KB
// double buffer) + kt12 staged once into a dedicated slot (6 barriers), all 10
// field rows preloaded (MLP), sig depth-1 prefetch, b1 folded into acc C-init,
// norm sig from per-wave LDS stash, XCD-bijective swizzle.
__global__ __launch_bounds__(512, 4) void atu_main(
    const float* __restrict__ pos, const float* __restrict__ sig,
    const float* __restrict__ offs,
    const float* __restrict__ b1, const float* __restrict__ b2,
    const unsigned short* __restrict__ fpad, const unsigned short* __restrict__ wall,
    float* __restrict__ out_stab, float* __restrict__ out_pos)
{
  __shared__ unsigned short ldsw[2][8192];           // 2 x 16KB weight buffers
  __shared__ unsigned short lds12[4096];             // 8KB dedicated kt12 slot
  __shared__ alignas(16) unsigned short ns[8][2048]; // 8 x 4KB per-wave sig stash
  const int tid  = threadIdx.x;
  const int lane = tid & 63;
  const int lg   = lane >> 4, lm = lane & 15;
  const int wid  = tid >> 6;
  int bid = blockIdx.x;
  int swz = (bid & 7) * 256 + (bid >> 3);      // XCD-bijective (2048 % 8 == 0)
  const int ub = swz * 128 + wid * 16;         // 16 units per wave
  const int un = ub + lm;                      // this lane-group's unit
  char* nsb = (char*)&ns[wid][0];
  const char* wallb = (const char*)wall;
  const char* fpadb = (const char*)fpad;

  // gather bases: ev0 / ev1
  int abase[2];
  {
    float px = pos[un * 3 + 0], py = pos[un * 3 + 1], pz = pos[un * 3 + 2];
    float qx = px + offs[un * 3 + 0], qy = py + offs[un * 3 + 1], qz = pz + offs[un * 3 + 2];
    int ax = min(max((int)px, 0), GG - 1), ay = min(max((int)py, 0), GG - 1), az = min(max((int)pz, 0), GG - 1);
    int bx = min(max((int)qx, 0), GG - 1), by = min(max((int)qy, 0), GG - 1), bz = min(max((int)qz, 0), GG - 1);
    abase[0] = ((ax + 3) * PG + (ay + 3)) * PG + (az + 3);
    abase[1] = ((bx + 3) * PG + (by + 3)) * PG + (bz + 3);
  }

  // async weight staging: pair (KTA, KTA+1) -> buffer H.
#define GLL2(KTA, H)                                                              \
  __builtin_amdgcn_global_load_lds(                                               \
      (const unsigned*)(wallb + (((KTA) * 512 + tid) * 16)),                      \
      (unsigned*)((char*)&ldsw[H][0] + wid * 1024), 16, 0, 0);                    \
  __builtin_amdgcn_global_load_lds(                                               \
      (const unsigned*)(wallb + ((((KTA) + 1) * 512 + tid) * 16)),                \
      (unsigned*)((char*)&ldsw[H][0] + 8192 + wid * 1024), 16, 0, 0);

  // ---- prologue: stage pair (0,1) AND kt12 (dedicated slot, covered by barrier #1);
  //      preload sig kt0 and ALL 10 field rows ----
  GLL2(0, 0)
  __builtin_amdgcn_global_load_lds(
      (const unsigned*)(wallb + ((12 * 512 + tid) * 16)),
      (unsigned*)((char*)lds12 + wid * 1024), 16, 0, 0);
  f32x4 spa = *(const f32x4*)(sig + (size_t)un * DD + lg * 8);
  f32x4 spb = *(const f32x4*)(sig + (size_t)un * DD + lg * 8 + 4);
  short8 rw[5][2];                              // all rows, both evs, in flight now
#pragma unroll
  for (int k = 0; k < 5; ++k) {
    int rd = ROWD.v[k * 4 + lg];
    rw[k][0] = *(const short8*)(fpadb + 2 * (size_t)(abase[0] + rd));
    rw[k][1] = *(const short8*)(fpadb + 2 * (size_t)(abase[1] + rd));
  }

  // acc C-init = b1 (bias folded)
  f32x4 acc[8][2];
#pragma unroll
  for (int nt = 0; nt < 8; ++nt) acc[nt][0] = *(const f32x4*)(b1 + nt * 16 + lg * 4);
  f32x4 acc2[8][2];
  unsigned Q[2][8][2];

  __syncthreads();   // barrier #1: pair (0,1) + kt12 landed

#define SIG_KT(KT, HALF)                                                          \
  {                                                                               \
    f32x4 na, nb;                                                                 \
    if ((KT) < 3) {                                                               \
      na = *(const f32x4*)(sig + (size_t)un * DD + ((KT) + 1) * 32 + lg * 8);     \
      nb = *(const f32x4*)(sig + (size_t)un * DD + ((KT) + 1) * 32 + lg * 8 + 4); \
    }                                                                             \
    Frag B;                                                                       \
    B.u[0] = cvtpk(spa[0], spa[1]); B.u[1] = cvtpk(spa[2], spa[3]);               \
    B.u[2] = cvtpk(spb[0], spb[1]); B.u[3] = cvtpk(spb[2], spb[3]);               \
    *(short8*)(nsb + ((KT) * 4 + lg) * 256 + lm * 16) = B.s;                      \
    const char* buf = (const char*)&ldsw[HALF][0] + (((KT) & 1) ? 8192 : 0);      \
    _Pragma("unroll")                                                             \
    for (int nt = 0; nt < 8; ++nt) {                                              \
      short8 af = *(const short8*)(buf + (nt * 64 + lane) * 16);                  \
      acc[nt][0] = __builtin_amdgcn_mfma_f32_16x16x32_bf16(af, B.s, acc[nt][0], 0, 0, 0); \
    }                                                                             \
    if ((KT) < 3) { spa = na; spb = nb; }                                         \
  }

#define ROW_KT(KT, HALF)                                                          \
  {                                                                               \
    const char* buf = (const char*)&ldsw[HALF][0] + (((KT) & 1) ? 8192 : 0);      \
    _Pragma("unroll")                                                             \
    for (int nt = 0; nt < 8; ++nt) {                                              \
      short8 af = *(const short8*)(buf + (nt * 64 + lane) * 16);                  \
      acc[nt][0] = __builtin_amdgcn_mfma_f32_16x16x32_bf16(af, rw[(KT) - 4][0], acc[nt][0], 0, 0, 0); \
      acc[nt][1] = __builtin_amdgcn_mfma_f32_16x16x32_bf16(af, rw[(KT) - 4][1], acc[nt][1], 0, 0, 0); \
    }                                                                             \
  }

#define G2_KT(KT, BUF)                                                            \
  {                                                                               \
    constexpr int kb = (KT) - 9;                                                  \
    Frag W[2];                                                                    \
    _Pragma("unroll")                                                             \
    for (int ut = 0; ut < 2; ++ut) {                                              \
      int qa0 = (int)Q[ut][2 * kb][0],     qa1 = (int)Q[ut][2 * kb][1];           \
      int qb0 = (int)Q[ut][2 * kb + 1][0], qb1 = (int)Q[ut][2 * kb + 1][1];       \
      int r00 = __builtin_amdgcn_ds_bpermute(ad0, qa0);                           \
      int r01 = __builtin_amdgcn_ds_bpermute(ad0, qa1);                           \
      int r10 = __builtin_amdgcn_ds_bpermute(ad1, qa0);                           \
      int r11 = __builtin_amdgcn_ds_bpermute(ad1, qa1);                           \
      int s00 = __builtin_amdgcn_ds_bpermute(ad0, qb0);                           \
      int s01 = __builtin_amdgcn_ds_bpermute(ad0, qb1);                           \
      int s10 = __builtin_amdgcn_ds_bpermute(ad1, qb0);                           \
      int s11 = __builtin_amdgcn_ds_bpermute(ad1, qb1);                           \
      W[ut].u[0] = (unsigned)(hi ? s00 : r00);                                    \
      W[ut].u[1] = (unsigned)(hi ? s01 : r01);                                    \
      W[ut].u[2] = (unsigned)(hi ? s10 : r10);                                    \
      W[ut].u[3] = (unsigned)(hi ? s11 : r11);                                    \
    }                                                                             \
    const char* buf = (BUF);                                                      \
    _Pragma("unroll")                                                             \
    for (int nt = 0; nt < 8; ++nt) {                                              \
      short8 af = *(const short8*)(buf + (nt * 64 + lane) * 16);                  \
      acc2[nt][0] = __builtin_amdgcn_mfma_f32_16x16x32_bf16(af, W[0].s, acc2[nt][0], 0, 0, 0); \
      acc2[nt][1] = __builtin_amdgcn_mfma_f32_16x16x32_bf16(af, W[1].s, acc2[nt][1], 0, 0, 0); \
    }                                                                             \
  }

  const int ad0 = ((((2 * lg) & 3) * 16) + lm) * 4;       // bpermute byte addrs
  const int ad1 = ((((2 * lg + 1) & 3) * 16) + lm) * 4;
  const bool hi = (lg >= 2);

  // P0: kts 0,1 from buf0; prefetch pair (2,3) -> buf1
  GLL2(2, 1)
  SIG_KT(0, 0) SIG_KT(1, 0)
  __syncthreads();

  // P1: kts 2,3 from buf1; prefetch pair (4,5) -> buf0
  GLL2(4, 0)
  SIG_KT(2, 1) SIG_KT(3, 1)
  __syncthreads();

  // sig contribution is shared by both evs (b1 carried along)
#pragma unroll
  for (int nt = 0; nt < 8; ++nt) acc[nt][1] = acc[nt][0];

  // P2: kts 4,5 from buf0; prefetch pair (6,7) -> buf1
  GLL2(6, 1)
  ROW_KT(4, 0) ROW_KT(5, 0)
  __syncthreads();

  // P3: kts 6,7 from buf1; prefetch pair (8,9) -> buf0
  GLL2(8, 0)
  ROW_KT(6, 1) ROW_KT(7, 1)
  __syncthreads();

  // P4: kt8 (row) + tanh/pack + kt9 (G2) from buf0; prefetch pair (10,11) -> buf1
  GLL2(10, 1)
  ROW_KT(8, 0)

  // tanh + pack h (bias already in acc)
#pragma unroll
  for (int nt = 0; nt < 8; ++nt) {
#pragma unroll
    for (int ut = 0; ut < 2; ++ut) {
      float h0 = fast_tanh(acc[nt][ut][0]);
      float h1 = fast_tanh(acc[nt][ut][1]);
      float h2 = fast_tanh(acc[nt][ut][2]);
      float h3 = fast_tanh(acc[nt][ut][3]);
      Q[ut][nt][0] = cvtpk(h0, h1);
      Q[ut][nt][1] = cvtpk(h2, h3);
    }
  }
#pragma unroll
  for (int nt = 0; nt < 8; ++nt) {
    f32x4 b2v = *(const f32x4*)(b2 + nt * 16 + lg * 4);
    acc2[nt][0] = b2v; acc2[nt][1] = b2v;
  }

  G2_KT(9, (const char*)&ldsw[0][0] + 8192)
  __syncthreads();

  // P5: kts 10,11 from buf1; kt12 already resident in its own slot -> no more syncs
  G2_KT(10, (const char*)&ldsw[1][0])
  G2_KT(11, (const char*)&ldsw[1][0] + 8192)
  G2_KT(12, (const char*)lds12)

  // ---- || resp - sig ||^2 (sig bf16 from per-wave LDS stash) ----
  float ssq[2] = {0.f, 0.f};
#pragma unroll
  for (int nt = 0; nt < 8; ++nt) {
    unsigned long long w64 = *(const unsigned long long*)
        (nsb + (nt * 2 + (lg >> 1)) * 256 + lm * 16 + (lg & 1) * 8);
    unsigned w0 = (unsigned)w64, w1 = (unsigned)(w64 >> 32);
    float sv0 = unplo(w0), sv1 = unphi(w0);
    float sv2 = unplo(w1), sv3 = unphi(w1);
#pragma unroll
    for (int ut = 0; ut < 2; ++ut) {
      float d0 = acc2[nt][ut][0] - sv0;
      float d1 = acc2[nt][ut][1] - sv1;
      float d2 = acc2[nt][ut][2] - sv2;
      float d3 = acc2[nt][ut][3] - sv3;
      ssq[ut] = fmaf(d0, d0, ssq[ut]);
      ssq[ut] = fmaf(d1, d1, ssq[ut]);
      ssq[ut] = fmaf(d2, d2, ssq[ut]);
      ssq[ut] = fmaf(d3, d3, ssq[ut]);
    }
  }
  ssq[0] += __shfl_xor(ssq[0], 16, 64); ssq[0] += __shfl_xor(ssq[0], 32, 64);
  ssq[1] += __shfl_xor(ssq[1], 16, 64); ssq[1] += __shfl_xor(ssq[1], 32, 64);

  // ---- accept / outputs: lanes 0..15, natural order (coalesced) ----
  if (lane < 16) {
    float px = pos[un * 3 + 0], py = pos[un * 3 + 1], pz = pos[un * 3 + 2];
    float ox = offs[un * 3 + 0], oy = offs[un * 3 + 1], oz = offs[un * 3 + 2];
    bool ok = ssq[1] <= ssq[0];
    out_stab[un] = sqrtf(ok ? ssq[1] : ssq[0]);
    out_pos[un * 3 + 0] = ok ? px + ox : px;
    out_pos[un * 3 + 1] = ok ? py + oy : py;
    out_pos[un * 3 + 2] = ok ? pz + oz : pz;
  }
#undef GLL2
#undef SIG_KT
#undef ROW_KT
#undef G2_KT
}

extern "C" void kernel_launch(void* const* d_in, const int* in_sizes, int n_in,
                              void* d_out, int out_size, void* d_ws, size_t ws_size,
                              hipStream_t stream) {
  const float* field = (const float*)d_in[0];
  const float* pos   = (const float*)d_in[1];
  const float* sig   = (const float*)d_in[2];
  const float* offs  = (const float*)d_in[3];
  const float* W1    = (const float*)d_in[4];
  const float* b1    = (const float*)d_in[5];
  const float* W2    = (const float*)d_in[6];
  const float* b2    = (const float*)d_in[7];
  float* out_stab = (float*)d_out;
  float* out_pos  = out_stab + NU;

  char* ws = (char*)d_ws;
  unsigned short* fpad = (unsigned short*)ws;                 // 4,812,208 B (+slack)
  unsigned short* wall = (unsigned short*)(ws + 4812800);     // 106,496 B (13 x 8KB)

  prep_field<<<(PG * PG * PG + 255) / 256, 256, 0, stream>>>(field, fpad);
  prep_w<<<26, 256, 0, stream>>>(W1, W2, wall);
  atu_main<<<NU / 128, 512, 0, stream>>>(pos, sig, offs, b1, b2,
                                         fpad, wall, out_stab, out_pos);
}